// Round 10
// baseline (82.684 us; speedup 1.0000x reference)
//
#include <hip/hip_runtime.h>
#include <hip/hip_fp16.h>

// RoIAlign (legacy, grid spacing roi/(P-1), PH=PW=8, zero for OOR samples)
// fused with 2x2 stride-1 max-pool -> out [R, C=256, 7, 7] float32.
//
// R10: (1) transpose v2 — block owns 64 hw x ALL 256 c, LDS-staged, writes
// full 512B records contiguously (R9 transpose wrote 128B fragments at
// 512B stride -> partial-line HBM writes). (2) DMA main kernel: issue_row
// moved to right after the barrier (before compute) for one extra compute
// phase of latency cover. Everything else = R9 (best known).

#define FH 200
#define FW 272
#define FC 256
#define FHW (FH * FW)          // 54400
#define SPATIAL_SCALE 0.25f
#define RECB 512               // bytes per pixel record (256 ch * 2 B)
#define ROWB (FW * RECB)       // bytes per feature row
#define NBLK 512               // persistent grid (2 blocks/CU * 256 CU)

// ------- transpose v2: [B,C,HW] f32 -> [B,HW,C] f16, full-record writes ----
__global__ __launch_bounds__(256) void transpose_f16v2_kernel(
    const float* __restrict__ in, __half* __restrict__ outT)
{
    __shared__ __half s_t[64][258];   // stride 258 f16 = 129 dw (odd) ~33 KB
    const int hw0  = blockIdx.x * 64;
    const int b    = blockIdx.y;
    const int tid  = threadIdx.x;
    const int lane = tid & 63;
    const int sub  = tid >> 6;        // 0..3

    const float* inb = in + (size_t)b * FC * FHW + hw0 + lane;
    #pragma unroll
    for (int chunk = 0; chunk < 4; ++chunk) {
        #pragma unroll
        for (int i = 0; i < 16; ++i) {
            const int c = chunk * 64 + sub * 16 + i;
            s_t[lane][c] = __float2half(inb[(size_t)c * FHW]);
        }
    }
    __syncthreads();

    // write 64 records x 512 B contiguous, u32 granularity (2-way LDS ok)
    uint32_t* outb = (uint32_t*)(outT + (size_t)b * FHW * FC) + (size_t)hw0 * 128;
    #pragma unroll
    for (int j = 0; j < 32; ++j) {
        const int idx = j * 256 + tid;        // u32 index within 32 KB tile
        const int hw  = idx >> 7;             // /128
        const int c2  = idx & 127;
        const uint32_t v = *(const uint32_t*)&s_t[hw][c2 * 2];
        outb[idx] = v;
    }
}

// ---------------- main: DMA-staged gather + fused pool --------------------
__global__ __launch_bounds__(256, 2) void roi_align_max_dma_kernel(
    const __half* __restrict__ featT,   // [B, H, W, C] f16
    const float* __restrict__ rois,     // [R, 5]
    float* __restrict__ out,            // [R, C, 7, 7]
    int R)
{
    __shared__ int      s_boff[64];         // record byte offset per grid pt
    __shared__ float    s_w0[64], s_w1[64], s_w2[64], s_w3[64];
    __shared__ uint32_t s_buf[3][4096];     // 3 x 16 KB row staging
    __shared__ __half   s_out16[FC * 49];   // 24.5 KB pooled output

    const int tid  = threadIdx.x;
    const int lane = tid & 63;
    const int wid  = tid >> 6;     // wave 0..3
    const int cp   = tid & 127;    // channel pair: channels 2cp, 2cp+1
    const int h    = tid >> 7;     // pw-half: 0 -> pw 0..3, 1 -> pw 3..7
    const char* fbytes = (const char*)featT;

    // issue one aligned row's 16 x 1KB chunks (4 per wave) via DMA
    auto issue_row = [&](int row) {
        const int rm  = row * 8;
        const int bsel = row % 3;
        #pragma unroll
        for (int i = 0; i < 4; ++i) {
            const int q  = wid * 4 + i;     // chunk 0..15
            const int fr = q >> 3;          // feature row 0/1
            const int pw = q & 7;           // grid col
            const char* g = fbytes + s_boff[rm + pw] + fr * ROWB + lane * 16;
            __builtin_amdgcn_global_load_lds(
                (const uint32_t*)g, &s_buf[bsel][q * 256], 16, 0, 0);
        }
    };

    for (int r = blockIdx.x; r < R; r += NBLK) {
        // ---- per-roi setup (64 grid points) ----
        if (tid < 64) {
            const float b  = rois[r * 5 + 0];
            const float x1 = rois[r * 5 + 1] * SPATIAL_SCALE;
            const float y1 = rois[r * 5 + 2] * SPATIAL_SCALE;
            const float x2 = rois[r * 5 + 3] * SPATIAL_SCALE;
            const float y2 = rois[r * 5 + 4] * SPATIAL_SCALE;
            const float bin_h = fmaxf(y2 - y1, 0.0f) * (1.0f / 7.0f);
            const float bin_w = fmaxf(x2 - x1, 0.0f) * (1.0f / 7.0f);

            const int ph = tid >> 3;
            const int pw = tid & 7;
            const float hh = y1 + (float)ph * bin_h;
            const float ww = x1 + (float)pw * bin_w;

            const bool valid = (hh >= 0.0f) && (hh < (float)FH) &&
                               (ww >= 0.0f) && (ww < (float)FW);
            // legacy: clip floor() into [0, H-2]; fractions NOT re-clamped
            const float h0 = fminf(fmaxf(floorf(hh), 0.0f), (float)(FH - 2));
            const float w0 = fminf(fmaxf(floorf(ww), 0.0f), (float)(FW - 2));
            const float fh = hh - h0;
            const float fw = ww - w0;
            const float v  = valid ? 1.0f : 0.0f;

            s_boff[tid] = ((int)b * FHW + (int)h0 * FW + (int)w0) * RECB;
            s_w0[tid] = (1.0f - fh) * (1.0f - fw) * v;
            s_w1[tid] = (1.0f - fh) * fw * v;
            s_w2[tid] = fh * (1.0f - fw) * v;
            s_w3[tid] = fh * fw * v;
        }
        __syncthreads();

        issue_row(0);
        issue_row(1);

        const int npt = h ? 5 : 4;      // points this half computes
        const int ncm = h ? 4 : 3;      // col-max outputs
        const int pw0 = h ? 3 : 0;
        const int owb = h ? 3 : 0;
        float2 prev[4];

        #pragma unroll
        for (int ar = 0; ar < 8; ++ar) {
            if (ar == 7) { asm volatile("s_waitcnt vmcnt(0)" ::: "memory"); }
            else         { asm volatile("s_waitcnt vmcnt(4)" ::: "memory"); }
            __builtin_amdgcn_sched_barrier(0);
            __builtin_amdgcn_s_barrier();

            // issue 2 rows ahead FIRST (buffer safe: (ar+2)%3 was last read
            // in compute(ar-1), finished by all waves before this barrier)
            if (ar < 6) issue_row(ar + 2);

            // compute aligned row ar from staged LDS
            const __half2* bh2 = (const __half2*)s_buf[ar % 3];
            float2 v[5];
            #pragma unroll
            for (int k = 0; k < 5; ++k) {
                if (k < npt) {
                    const int pw = pw0 + k;
                    const int m  = ar * 8 + pw;
                    const float2 a00 = __half22float2(bh2[pw * 256 + cp]);
                    const float2 a01 = __half22float2(bh2[pw * 256 + 128 + cp]);
                    const float2 a10 = __half22float2(bh2[(8 + pw) * 256 + cp]);
                    const float2 a11 = __half22float2(bh2[(8 + pw) * 256 + 128 + cp]);
                    const float w0v = s_w0[m], w1v = s_w1[m];
                    const float w2v = s_w2[m], w3v = s_w3[m];
                    v[k].x = a00.x * w0v + a01.x * w1v + a10.x * w2v + a11.x * w3v;
                    v[k].y = a00.y * w0v + a01.y * w1v + a10.y * w2v + a11.y * w3v;
                }
            }
            float2 cur[4];
            #pragma unroll
            for (int j = 0; j < 4; ++j) {
                if (j < ncm) {
                    cur[j].x = fmaxf(v[j].x, v[j + 1].x);
                    cur[j].y = fmaxf(v[j].y, v[j + 1].y);
                }
            }
            if (ar > 0) {
                const int ob = (ar - 1) * 7 + owb;
                #pragma unroll
                for (int j = 0; j < 4; ++j) {
                    if (j < ncm) {
                        s_out16[(2 * cp)     * 49 + ob + j] =
                            __float2half(fmaxf(prev[j].x, cur[j].x));
                        s_out16[(2 * cp + 1) * 49 + ob + j] =
                            __float2half(fmaxf(prev[j].y, cur[j].y));
                    }
                }
            }
            #pragma unroll
            for (int j = 0; j < 4; ++j) prev[j] = cur[j];
        }
        __syncthreads();

        // dense float4 writeout (f16 -> f32) of this roi's [C,7,7] slab
        float4* o4 = (float4*)(out + (size_t)r * (FC * 49));
        #pragma unroll
        for (int k = 0; k < 13; ++k) {
            const int idx = k * 256 + tid;      // group of 4 halves
            if (idx < (FC * 49 / 4)) {
                const __half2* sh2 = (const __half2*)(s_out16 + idx * 4);
                const float2 lo = __half22float2(sh2[0]);
                const float2 hi = __half22float2(sh2[1]);
                o4[idx] = make_float4(lo.x, lo.y, hi.x, hi.y);
            }
        }
        __syncthreads();   // s_out16/s_buf safe to reuse for next roi
    }
}

// ---------------- fallback (NCHW direct) if ws too small ------------------
__global__ __launch_bounds__(256) void roi_align_max_kernel(
    const float* __restrict__ feat, const float* __restrict__ rois,
    float* __restrict__ out, int R)
{
    __shared__ int   s_off[64];
    __shared__ float s_w0[64], s_w1[64], s_w2[64], s_w3[64];
    __shared__ int   s_base;

    const int r   = blockIdx.x;
    const int tid = threadIdx.x;

    if (tid < 64) {
        const float b  = rois[r * 5 + 0];
        const float x1 = rois[r * 5 + 1] * SPATIAL_SCALE;
        const float y1 = rois[r * 5 + 2] * SPATIAL_SCALE;
        const float x2 = rois[r * 5 + 3] * SPATIAL_SCALE;
        const float y2 = rois[r * 5 + 4] * SPATIAL_SCALE;
        const float bin_h = fmaxf(y2 - y1, 0.0f) * (1.0f / 7.0f);
        const float bin_w = fmaxf(x2 - x1, 0.0f) * (1.0f / 7.0f);
        const int ph = tid >> 3;
        const int pw = tid & 7;
        const float h = y1 + (float)ph * bin_h;
        const float w = x1 + (float)pw * bin_w;
        const bool valid = (h >= 0.0f) && (h < (float)FH) &&
                           (w >= 0.0f) && (w < (float)FW);
        const float h0 = fminf(fmaxf(floorf(h), 0.0f), (float)(FH - 2));
        const float w0 = fminf(fmaxf(floorf(w), 0.0f), (float)(FW - 2));
        const float fh = h - h0;
        const float fw = w - w0;
        const float v  = valid ? 1.0f : 0.0f;
        s_off[tid] = (int)h0 * FW + (int)w0;
        s_w0[tid] = (1.0f - fh) * (1.0f - fw) * v;
        s_w1[tid] = (1.0f - fh) * fw * v;
        s_w2[tid] = fh * (1.0f - fw) * v;
        s_w3[tid] = fh * fw * v;
        if (tid == 0) s_base = (int)b * (FC * FHW);
    }
    __syncthreads();

    const int c = tid;
    const float* __restrict__ f = feat + s_base + c * FHW;
    float* __restrict__ outp = out + ((size_t)r * FC + c) * 49;

    float prev[8];
    for (int ph = 0; ph < 8; ++ph) {
        float cur[8];
        #pragma unroll
        for (int pw = 0; pw < 8; ++pw) {
            const int m = ph * 8 + pw;
            const int o = s_off[m];
            cur[pw] = f[o] * s_w0[m] + f[o + 1] * s_w1[m]
                    + f[o + FW] * s_w2[m] + f[o + FW + 1] * s_w3[m];
        }
        if (ph > 0) {
            #pragma unroll
            for (int ow = 0; ow < 7; ++ow)
                outp[(ph - 1) * 7 + ow] =
                    fmaxf(fmaxf(prev[ow], prev[ow + 1]),
                          fmaxf(cur[ow],  cur[ow + 1]));
        }
        #pragma unroll
        for (int pw = 0; pw < 8; ++pw) prev[pw] = cur[pw];
    }
}

extern "C" void kernel_launch(void* const* d_in, const int* in_sizes, int n_in,
                              void* d_out, int out_size, void* d_ws, size_t ws_size,
                              hipStream_t stream) {
    const float* feat = (const float*)d_in[0];
    const float* rois = (const float*)d_in[1];
    float* out = (float*)d_out;
    const int R = in_sizes[1] / 5;
    if (R <= 0) return;

    const size_t needed = (size_t)2 * FC * FHW * sizeof(__half);  // 55.7 MB
    if (ws_size >= needed) {
        __half* featT = (__half*)d_ws;
        transpose_f16v2_kernel<<<dim3(FHW / 64, 2), 256, 0, stream>>>(feat, featT);
        const int nblk = (R < NBLK) ? R : NBLK;
        roi_align_max_dma_kernel<<<nblk, 256, 0, stream>>>(featT, rois, out, R);
    } else {
        roi_align_max_kernel<<<R, 256, 0, stream>>>(feat, rois, out, R);
    }
}